// Round 17
// baseline (390.585 us; speedup 1.0000x reference)
//
#include <hip/hip_runtime.h>

// ElmanRNN via MFMA, v12 = v11 numerics with 4 waves x 2 col-tiles/wave.
// BATCH=4096, SEQ=512, IN=2, HID=128, OUT=1
//
// R15 model: step time ~ LDS pipe queue drain. After each barrier all waves
// issue their h-reads into the ONE per-CU LDS pipe: 8 waves x 8 ds_read_b128
// = 64 reads x ~12cy ~ 800cy queue + ~500cy tail + barrier ~ 1640cy measured.
//
// v12: 4 waves (256 thr), each owns 32 j-cols as TWO 16-col tiles sharing one
// set of h-fragment reads -> 32 reads/step queue (~400cy). Per-j arithmetic
// is BIT-IDENTICAL to v11 (same op sequence, same K-order; only the j->wave
// mapping changes) -> absmax must stay exactly 1.953e-3. Writes stay 16 b64;
// per-SIMD VALU/trans totals unchanged (1 wave x 2x work). Risk: 1 wave/SIMD
// (no TLP) — if time is flat, the step is path-bound, not queue-bound.
//
// Kept from v11: x via per-lane register prefetch (no x LDS), lgkmcnt-only
// step barrier, full 4-bit XOR swizzle, unroll-2 ping-pong, operand-swapped
// 3-product split GEMM, __expf/__fdividef tanh, cvt_pk pack.

constexpr int BATCH   = 4096;
constexpr int SEQ     = 512;
constexpr int INP     = 2;
constexpr int HID     = 128;
constexpr int BM      = 16;    // batch rows per block
constexpr int THREADS = 256;   // 4 waves, 1 block/CU, 1 wave/SIMD

typedef short bf16x8 __attribute__((ext_vector_type(8)));
typedef float f32x4  __attribute__((ext_vector_type(4)));

__device__ inline unsigned short f2bf(float f) {          // round-to-nearest-even
    unsigned u = __float_as_uint(f);
    return (unsigned short)((u + 0x7FFFu + ((u >> 16) & 1u)) >> 16);
}
__device__ inline float bf2f(unsigned short s) {
    return __uint_as_float(((unsigned)s) << 16);
}
__device__ inline unsigned cvt_pk_bf16(float a, float b) { // lo=bf(a), hi=bf(b)
    unsigned r;
    asm("v_cvt_pk_bf16_f32 %0, %1, %2" : "=v"(r) : "v"(a), "v"(b));
    return r;
}
// LDS-only barrier: drains ds ops, rendezvous; leaves VMEM (x prefetch)
// in flight.
__device__ inline void lds_barrier() {
    asm volatile("s_waitcnt lgkmcnt(0)\n\ts_barrier" ::: "memory");
}

__global__ __launch_bounds__(THREADS, 1)
void elman_mfma12(const float* __restrict__ x,
                  const float* __restrict__ W_ih,
                  const float* __restrict__ b_ih,
                  const float* __restrict__ W_ho,
                  const float* __restrict__ b_ho,
                  float* __restrict__ out)
{
    __shared__ unsigned short hlds[2][2][BM][HID];  // [buf][hi/lo][r][j] = 16 KB
    __shared__ float red[BM][4];                    // epilogue partials

    const int tid  = threadIdx.x;
    const int lane = tid & 63;
    const int w    = tid >> 6;        // wave id 0..3 -> j range [32w, 32w+32)
    const int l15  = lane & 15;
    const int g    = lane >> 4;       // 0..3
    const int B0   = blockIdx.x * BM;

    // ---- stationary W fragments (A-operand) for BOTH tiles, hi/lo split ----
    // tile c: lane's A-row jA = 32w + 16c + l15; slot (g,i) kt <- W[jA][k]
    bf16x8 whi[2][4], wlo[2][4];
    #pragma unroll
    for (int c = 0; c < 2; ++c) {
        const float* Wrow = W_ih + (size_t)(w * 32 + c * 16 + l15) * (INP + HID) + INP;
        #pragma unroll
        for (int kt = 0; kt < 4; ++kt) {
            const int k0 = kt * 32 + g * 8;
            #pragma unroll
            for (int i = 0; i < 8; ++i) {
                const float wv = Wrow[k0 + i];
                const unsigned short hi = f2bf(wv);
                whi[c][kt][i] = (short)hi;
                wlo[c][kt][i] = (short)f2bf(wv - bf2f(hi));
            }
        }
    }

    // ---- per-reg coefficients for the 8 j's this lane RECEIVES in D ----
    // D (tile c): col = l15 = batch row, row = g*4+reg -> jj = 32w+16c+g*4+reg
    float wx0v[2][4], wx1v[2][4], bjv[2][4], whov[2][4];
    #pragma unroll
    for (int c = 0; c < 2; ++c)
        #pragma unroll
        for (int reg = 0; reg < 4; ++reg) {
            const int jj = w * 32 + c * 16 + g * 4 + reg;
            const float* Wr = W_ih + (size_t)jj * (INP + HID);
            wx0v[c][reg] = Wr[0];
            wx1v[c][reg] = Wr[1];
            bjv[c][reg]  = b_ih[jj];
            whov[c][reg] = W_ho[jj];
        }

    // ---- hoisted swizzled LDS offsets (key = l15<<4, full 4 bits) ----
    int roff[4];
    #pragma unroll
    for (int kt = 0; kt < 4; ++kt)
        roff[kt] = l15 * 256 + ((kt * 64 + g * 16) ^ (l15 << 4));
    // write (tile c): row l15, logical in-row byte 2*j0 = 64w + 32c + 8g.
    // bits>=4 go through XOR; bit3 ((g&1)*8) added outside.
    int woff[2];
    #pragma unroll
    for (int c = 0; c < 2; ++c)
        woff[c] = l15 * 256 + ((w * 64 + c * 32 + (g & 2) * 8) ^ (l15 << 4)) + (g & 1) * 8;

    // ---- h0 = 0 (16 KB = 1024 float4; 256 threads x 4) ----
    #pragma unroll
    for (int q = 0; q < 4; ++q)
        reinterpret_cast<float4*>(hlds)[tid + 256 * q] = float4{0.f, 0.f, 0.f, 0.f};

    // ---- per-lane x row; prime depth-2 prefetch (t=0, t=1) ----
    const float* xrow = x + (size_t)(B0 + l15) * (SEQ * INP);
    float2 xv0 = *reinterpret_cast<const float2*>(xrow);
    float2 xv1 = *reinterpret_cast<const float2*>(xrow + INP);

    __syncthreads();   // h0 visible

    char* hbA = (char*)&hlds[0][0][0][0];   // buf0 hi
    char* lbA = (char*)&hlds[0][1][0][0];   // buf0 lo
    char* hbB = (char*)&hlds[1][0][0][0];   // buf1 hi
    char* lbB = (char*)&hlds[1][1][0][0];   // buf1 lo

    float hv[2][4];                          // final-step h (row l15, 8 j's)
    #pragma unroll
    for (int c = 0; c < 2; ++c)
        #pragma unroll
        for (int reg = 0; reg < 4; ++reg) hv[c][reg] = 0.f;

    // one step: read (HP,LP) ONCE, two tiles of MFMA, write (HN,LN)
#define RNN_STEP(HP, LP, HN, LN, XV)                                           \
    {                                                                          \
        bf16x8 ahi[4], alo[4];                                                 \
        _Pragma("unroll")                                                      \
        for (int kt = 0; kt < 4; ++kt) {                                       \
            ahi[kt] = *reinterpret_cast<const bf16x8*>((HP) + roff[kt]);       \
            alo[kt] = *reinterpret_cast<const bf16x8*>((LP) + roff[kt]);       \
        }                                                                      \
        f32x4 a0[2], a1[2], a2[2];                                             \
        _Pragma("unroll")                                                      \
        for (int c = 0; c < 2; ++c) {                                          \
            a0[c] = f32x4{0.f, 0.f, 0.f, 0.f};                                 \
            a1[c] = f32x4{0.f, 0.f, 0.f, 0.f};                                 \
            a2[c] = f32x4{0.f, 0.f, 0.f, 0.f};                                 \
        }                                                                      \
        _Pragma("unroll")                                                      \
        for (int kt = 0; kt < 4; ++kt) {                                       \
            a0[0] = __builtin_amdgcn_mfma_f32_16x16x32_bf16(whi[0][kt], ahi[kt], a0[0], 0, 0, 0); \
            a1[0] = __builtin_amdgcn_mfma_f32_16x16x32_bf16(whi[0][kt], alo[kt], a1[0], 0, 0, 0); \
            a2[0] = __builtin_amdgcn_mfma_f32_16x16x32_bf16(wlo[0][kt], ahi[kt], a2[0], 0, 0, 0); \
            a0[1] = __builtin_amdgcn_mfma_f32_16x16x32_bf16(whi[1][kt], ahi[kt], a0[1], 0, 0, 0); \
            a1[1] = __builtin_amdgcn_mfma_f32_16x16x32_bf16(whi[1][kt], alo[kt], a1[1], 0, 0, 0); \
            a2[1] = __builtin_amdgcn_mfma_f32_16x16x32_bf16(wlo[1][kt], ahi[kt], a2[1], 0, 0, 0); \
        }                                                                      \
        const float2 xv = (XV);                                                \
        _Pragma("unroll")                                                      \
        for (int c = 0; c < 2; ++c) {                                          \
            float hcur[4];                                                     \
            _Pragma("unroll")                                                  \
            for (int reg = 0; reg < 4; ++reg) {                                \
                const float acc = (a0[c][reg] + a1[c][reg] + a2[c][reg])       \
                                + fmaf(wx0v[c][reg], xv.x,                     \
                                  fmaf(wx1v[c][reg], xv.y, bjv[c][reg]));      \
                const float e = __expf(acc + acc);                             \
                hcur[reg] = 1.0f - __fdividef(2.0f, e + 1.0f);  /* tanh */     \
                hv[c][reg] = hcur[reg];                                        \
            }                                                                  \
            const unsigned c01 = cvt_pk_bf16(hcur[0], hcur[1]);                \
            const unsigned c23 = cvt_pk_bf16(hcur[2], hcur[3]);                \
            const float h0b = __uint_as_float(c01 << 16);                      \
            const float h1b = __uint_as_float(c01 & 0xFFFF0000u);              \
            const float h2b = __uint_as_float(c23 << 16);                      \
            const float h3b = __uint_as_float(c23 & 0xFFFF0000u);              \
            const unsigned l01 = cvt_pk_bf16(hcur[0] - h0b, hcur[1] - h1b);    \
            const unsigned l23 = cvt_pk_bf16(hcur[2] - h2b, hcur[3] - h3b);    \
            *reinterpret_cast<uint2*>((HN) + woff[c]) = uint2{c01, c23};       \
            *reinterpret_cast<uint2*>((LN) + woff[c]) = uint2{l01, l23};       \
        }                                                                      \
        lds_barrier();                                                         \
    }

    #pragma unroll 1
    for (int t2 = 0; t2 < SEQ; t2 += 2) {
        // depth-2 prefetch for steps t2+2, t2+3 (clamped on last iter)
        const int tn = (t2 + 2 < SEQ) ? (t2 + 2) : 0;
        const float2 xn0 = *reinterpret_cast<const float2*>(xrow + (size_t)tn * INP);
        const float2 xn1 = *reinterpret_cast<const float2*>(xrow + (size_t)tn * INP + INP);

        RNN_STEP(hbA, lbA, hbB, lbB, xv0)       // even step: buf0 -> buf1
        RNN_STEP(hbB, lbB, hbA, lbA, xv1)       // odd step:  buf1 -> buf0

        xv0 = xn0;
        xv1 = xn1;
    }
#undef RNN_STEP

    // ---- epilogue: out[r] = sum_j Who[j]*h[r][j] + b_ho ----
    float part = 0.f;
    #pragma unroll
    for (int c = 0; c < 2; ++c)
        #pragma unroll
        for (int reg = 0; reg < 4; ++reg)
            part = fmaf(whov[c][reg], hv[c][reg], part);
    part += __shfl_xor(part, 16);   // sum over g bit0
    part += __shfl_xor(part, 32);   // sum over g bit1
    if (lane < 16) red[l15][w] = part;
    __syncthreads();
    if (tid < BM) {
        float s = b_ho[0];
        #pragma unroll
        for (int q = 0; q < 4; ++q) s += red[tid][q];
        out[B0 + tid] = s;
    }
}

extern "C" void kernel_launch(void* const* d_in, const int* in_sizes, int n_in,
                              void* d_out, int out_size, void* d_ws, size_t ws_size,
                              hipStream_t stream)
{
    (void)in_sizes; (void)n_in; (void)out_size; (void)d_ws; (void)ws_size;
    const float* x    = (const float*)d_in[0];
    const float* W_ih = (const float*)d_in[1];
    const float* b_ih = (const float*)d_in[2];
    const float* W_ho = (const float*)d_in[3];
    const float* b_ho = (const float*)d_in[4];
    float* out = (float*)d_out;

    dim3 grid(BATCH / BM);     // 256 blocks = 1 per CU
    dim3 block(THREADS);
    elman_mfma12<<<grid, block, 0, stream>>>(x, W_ih, b_ih, W_ho, b_ho, out);
}

// Round 19
// 303.684 us; speedup vs baseline: 1.2862x; 1.2862x over previous
//
#include <hip/hip_runtime.h>

// ElmanRNN via MFMA, v14 = v13 with CORRECT per-word pinning.
// BATCH=4096, SEQ=512, IN=2, HID=128, OUT=1
//
// R17 post-mortem: v13's pin_frag used ONE asm block with 4 movs and plain
// "=v" outputs (no early-clobber) -> output regs could alias later-read
// inputs -> first mov clobbered u[1..3] -> garbage W frags (absmax 1.19).
// v14 pins each 32-bit word in its OWN single-instruction asm: a single
// v_mov reads its input before writing, so aliasing is harmless. Hard-def
// semantics preserved: volatile asm output is non-rematerializable, forcing
// the value to stay loop-carried in a VGPR.
//
// Theory under test (from R16): v11's VGPR_Count=52 < ~65 live invariants
// => compiler rematerializes W frags every step (L2 reload + f2bf recompute),
// inflating VALUBusy to 62%. Pinning forces residency (budget 256 @ 2
// waves/EU; need ~110).
//
// Everything else byte-identical to v11 (302us champion): 8 waves,
// operand-swapped W.h^T 3-product split GEMM, full 4-bit XOR swizzle, b64
// packed writes, unroll-2 ping-pong, x via per-lane register prefetch,
// lgkmcnt-only step barrier, __expf/__fdividef tanh, cvt_pk pack.

constexpr int BATCH   = 4096;
constexpr int SEQ     = 512;
constexpr int INP     = 2;
constexpr int HID     = 128;
constexpr int BM      = 16;    // batch rows per block
constexpr int THREADS = 512;   // 8 waves, 1 block/CU, 2 waves/SIMD

typedef short bf16x8 __attribute__((ext_vector_type(8)));
typedef float f32x4  __attribute__((ext_vector_type(4)));
typedef unsigned int u32x4 __attribute__((ext_vector_type(4)));

__device__ inline unsigned short f2bf(float f) {          // round-to-nearest-even
    unsigned u = __float_as_uint(f);
    return (unsigned short)((u + 0x7FFFu + ((u >> 16) & 1u)) >> 16);
}
__device__ inline float bf2f(unsigned short s) {
    return __uint_as_float(((unsigned)s) << 16);
}
__device__ inline unsigned cvt_pk_bf16(float a, float b) { // lo=bf(a), hi=bf(b)
    unsigned r;
    asm("v_cvt_pk_bf16_f32 %0, %1, %2" : "=v"(r) : "v"(a), "v"(b));
    return r;
}
// HARD pin: one volatile single-instruction v_mov per 32-bit word. Single
// mov reads input before writing -> output/input aliasing harmless. The
// volatile def is non-rematerializable -> value stays loop-carried.
__device__ inline float pin_f(float v) {
    float r;
    asm volatile("v_mov_b32 %0, %1" : "=v"(r) : "v"(v));
    return r;
}
__device__ inline int pin_i(int v) {
    int r;
    asm volatile("v_mov_b32 %0, %1" : "=v"(r) : "v"(v));
    return r;
}
__device__ inline bf16x8 pin_frag(bf16x8 f) {
    u32x4 u = __builtin_bit_cast(u32x4, f);
    #pragma unroll
    for (int i = 0; i < 4; ++i)
        asm volatile("v_mov_b32 %0, %1" : "=v"(u[i]) : "v"(u[i]));
    return __builtin_bit_cast(bf16x8, u);
}
// LDS-only barrier: drains ds ops, rendezvous; leaves VMEM (x prefetch)
// in flight.
__device__ inline void lds_barrier() {
    asm volatile("s_waitcnt lgkmcnt(0)\n\ts_barrier" ::: "memory");
}

__global__ __launch_bounds__(THREADS, 2)
void elman_mfma14(const float* __restrict__ x,
                  const float* __restrict__ W_ih,
                  const float* __restrict__ b_ih,
                  const float* __restrict__ W_ho,
                  const float* __restrict__ b_ho,
                  float* __restrict__ out)
{
    __shared__ unsigned short hlds[2][2][BM][HID];  // [buf][hi/lo][r][j] = 16 KB
    __shared__ float red[BM][8];                    // epilogue partials

    const int tid  = threadIdx.x;
    const int lane = tid & 63;
    const int w    = tid >> 6;        // wave id 0..7 -> j-tile [16w, 16w+16)
    const int l15  = lane & 15;
    const int g    = lane >> 4;       // 0..3
    const int B0   = blockIdx.x * BM;

    // ---- stationary W fragments (A-operand), hi/lo bf16 split, PINNED ----
    bf16x8 whi[4], wlo[4];
    {
        const float* Wrow = W_ih + (size_t)(w * 16 + l15) * (INP + HID) + INP;
        #pragma unroll
        for (int kt = 0; kt < 4; ++kt) {
            const int k0 = kt * 32 + g * 8;
            #pragma unroll
            for (int i = 0; i < 8; ++i) {
                const float wv = Wrow[k0 + i];
                const unsigned short hi = f2bf(wv);
                whi[kt][i] = (short)hi;
                wlo[kt][i] = (short)f2bf(wv - bf2f(hi));
            }
        }
    }
    #pragma unroll
    for (int kt = 0; kt < 4; ++kt) {
        whi[kt] = pin_frag(whi[kt]);
        wlo[kt] = pin_frag(wlo[kt]);
    }

    // ---- per-reg coefficients for the 4 j's this lane RECEIVES in D ----
    float wx0v[4], wx1v[4], bjv[4], whov[4];
    #pragma unroll
    for (int reg = 0; reg < 4; ++reg) {
        const int jj = w * 16 + g * 4 + reg;
        const float* Wr = W_ih + (size_t)jj * (INP + HID);
        wx0v[reg] = pin_f(Wr[0]);
        wx1v[reg] = pin_f(Wr[1]);
        bjv[reg]  = pin_f(b_ih[jj]);
        whov[reg] = W_ho[jj];          // epilogue-only: not pinned
    }

    // ---- hoisted swizzled LDS offsets (key = r<<4, full 4 bits), PINNED ----
    int roff[4];
    #pragma unroll
    for (int kt = 0; kt < 4; ++kt)
        roff[kt] = pin_i(l15 * 256 + ((kt * 64 + g * 16) ^ (l15 << 4)));
    const int woff = pin_i(l15 * 256 + (((w * 32 + (g & 2) * 8)) ^ (l15 << 4)) + (g & 1) * 8);

    // ---- h0 = 0 ----
    reinterpret_cast<float4*>(hlds)[tid]       = float4{0.f, 0.f, 0.f, 0.f};
    reinterpret_cast<float4*>(hlds)[tid + 512] = float4{0.f, 0.f, 0.f, 0.f};

    // ---- per-lane x row; prime depth-2 prefetch (t=0, t=1) ----
    const float* xrow = x + (size_t)(B0 + l15) * (SEQ * INP);
    float2 xv0 = *reinterpret_cast<const float2*>(xrow);
    float2 xv1 = *reinterpret_cast<const float2*>(xrow + INP);

    __syncthreads();   // h0 visible

    char* hbA = (char*)&hlds[0][0][0][0];   // buf0 hi
    char* lbA = (char*)&hlds[0][1][0][0];   // buf0 lo
    char* hbB = (char*)&hlds[1][0][0][0];   // buf1 hi
    char* lbB = (char*)&hlds[1][1][0][0];   // buf1 lo

    float hv[4] = {0.f, 0.f, 0.f, 0.f};     // final-step h (row l15, 4 j's)

    // one step, EXACT v11 body: read (HP,LP), write (HN,LN)
#define RNN_STEP(HP, LP, HN, LN, XV)                                           \
    {                                                                          \
        bf16x8 ahi[4], alo[4];                                                 \
        _Pragma("unroll")                                                      \
        for (int kt = 0; kt < 4; ++kt) {                                       \
            ahi[kt] = *reinterpret_cast<const bf16x8*>((HP) + roff[kt]);       \
            alo[kt] = *reinterpret_cast<const bf16x8*>((LP) + roff[kt]);       \
        }                                                                      \
        f32x4 a0 = {0.f, 0.f, 0.f, 0.f};                                       \
        f32x4 a1 = {0.f, 0.f, 0.f, 0.f};                                       \
        f32x4 a2 = {0.f, 0.f, 0.f, 0.f};                                       \
        _Pragma("unroll")                                                      \
        for (int kt = 0; kt < 4; ++kt) {                                       \
            a0 = __builtin_amdgcn_mfma_f32_16x16x32_bf16(whi[kt], ahi[kt], a0, 0, 0, 0); \
            a1 = __builtin_amdgcn_mfma_f32_16x16x32_bf16(whi[kt], alo[kt], a1, 0, 0, 0); \
            a2 = __builtin_amdgcn_mfma_f32_16x16x32_bf16(wlo[kt], ahi[kt], a2, 0, 0, 0); \
        }                                                                      \
        const float2 xv = (XV);                                                \
        float hcur[4];                                                         \
        _Pragma("unroll")                                                      \
        for (int reg = 0; reg < 4; ++reg) {                                    \
            const float acc = (a0[reg] + a1[reg] + a2[reg])                    \
                            + fmaf(wx0v[reg], xv.x, fmaf(wx1v[reg], xv.y, bjv[reg])); \
            const float e = __expf(acc + acc);                                 \
            hcur[reg] = 1.0f - __fdividef(2.0f, e + 1.0f);   /* tanh(acc) */   \
            hv[reg]   = hcur[reg];                                             \
        }                                                                      \
        const unsigned c01 = cvt_pk_bf16(hcur[0], hcur[1]);                    \
        const unsigned c23 = cvt_pk_bf16(hcur[2], hcur[3]);                    \
        const float h0b = __uint_as_float(c01 << 16);                          \
        const float h1b = __uint_as_float(c01 & 0xFFFF0000u);                  \
        const float h2b = __uint_as_float(c23 << 16);                          \
        const float h3b = __uint_as_float(c23 & 0xFFFF0000u);                  \
        const unsigned l01 = cvt_pk_bf16(hcur[0] - h0b, hcur[1] - h1b);        \
        const unsigned l23 = cvt_pk_bf16(hcur[2] - h2b, hcur[3] - h3b);        \
        *reinterpret_cast<uint2*>((HN) + woff) = uint2{c01, c23};              \
        *reinterpret_cast<uint2*>((LN) + woff) = uint2{l01, l23};              \
        lds_barrier();                                                         \
    }

    #pragma unroll 1
    for (int t2 = 0; t2 < SEQ; t2 += 2) {
        // depth-2 prefetch for steps t2+2, t2+3 (clamped on last iter)
        const int tn = (t2 + 2 < SEQ) ? (t2 + 2) : 0;
        const float2 xn0 = *reinterpret_cast<const float2*>(xrow + (size_t)tn * INP);
        const float2 xn1 = *reinterpret_cast<const float2*>(xrow + (size_t)tn * INP + INP);

        RNN_STEP(hbA, lbA, hbB, lbB, xv0)       // even step: buf0 -> buf1
        RNN_STEP(hbB, lbB, hbA, lbA, xv1)       // odd step:  buf1 -> buf0

        xv0 = xn0;
        xv1 = xn1;
    }
#undef RNN_STEP

    // ---- epilogue: out[r] = sum_j Who[j]*h[r][j] + b_ho ----
    float part = 0.f;
    #pragma unroll
    for (int reg = 0; reg < 4; ++reg) part = fmaf(whov[reg], hv[reg], part);
    part += __shfl_xor(part, 16);   // sum over g bit0
    part += __shfl_xor(part, 32);   // sum over g bit1
    if (lane < 16) red[l15][w] = part;
    __syncthreads();
    if (tid < BM) {
        float s = b_ho[0];
        #pragma unroll
        for (int q = 0; q < 8; ++q) s += red[tid][q];
        out[B0 + tid] = s;
    }
}

extern "C" void kernel_launch(void* const* d_in, const int* in_sizes, int n_in,
                              void* d_out, int out_size, void* d_ws, size_t ws_size,
                              hipStream_t stream)
{
    (void)in_sizes; (void)n_in; (void)out_size; (void)d_ws; (void)ws_size;
    const float* x    = (const float*)d_in[0];
    const float* W_ih = (const float*)d_in[1];
    const float* b_ih = (const float*)d_in[2];
    const float* W_ho = (const float*)d_in[3];
    const float* b_ho = (const float*)d_in[4];
    float* out = (float*)d_out;

    dim3 grid(BATCH / BM);     // 256 blocks = 1 per CU
    dim3 block(THREADS);
    elman_mfma14<<<grid, block, 0, stream>>>(x, W_ih, b_ih, W_ho, b_ho, out);
}